// Round 21
// baseline (250.167 us; speedup 1.0000x reference)
//
#include <hip/hip_runtime.h>
#include <stdint.h>

// Round 21: attn flash split-KV. The r20 makespan (69us) == the qb=15
// block's latency wall (32 tiles x 2.21us/tile; co-residency can't shorten
// one block's barrier chain). Fix: qb>=8 splits into two half-KV blocks
// (9..16 tiles) writing raw partials (O in m-frame, l, m) to scratch (a1,
// dead during attn); merge kernel combines frames and writes obuf. 768
// blocks all co-resident at 3/CU (3x54272B LDS = 162816 <= 163840).
// Everything else frozen from round 20.

typedef unsigned short u16;
typedef unsigned int u32;
typedef __attribute__((ext_vector_type(4))) float f32x4;
typedef __attribute__((ext_vector_type(8))) short s16x8;

__device__ __forceinline__ u16 f2bf(float f) {
  u32 u = __builtin_bit_cast(u32, f);
  u += 0x7fffu + ((u >> 16) & 1u);
  return (u16)(u >> 16);
}
__device__ __forceinline__ s16x8 ld_s16x8_a8(const u16* p) {
  union { uint2 d[2]; s16x8 v; } u;
  u.d[0] = *(const uint2*)p;
  u.d[1] = *(const uint2*)(p + 4);
  return u.v;
}
__device__ __forceinline__ void gload16(const u16* g, u16* lds_base) {
  __builtin_amdgcn_global_load_lds(
      (const __attribute__((address_space(1))) void*)g,
      (__attribute__((address_space(3))) void*)lds_base, 16, 0, 0);
}

// ---------------------------------------------------------------------------
// Fused weight transposes fp32 -> bf16^T, one launch, 3072 blocks.
// ---------------------------------------------------------------------------
__global__ __launch_bounds__(256) void transpose_all_kernel(
    const float* __restrict__ Wq, const float* __restrict__ Wk,
    const float* __restrict__ Wv, const float* __restrict__ Wproj,
    const float* __restrict__ W1, const float* __restrict__ W2,
    u16* __restrict__ WqkvT, u16* __restrict__ WprojT,
    u16* __restrict__ W1T, u16* __restrict__ W2T) {
  const int bid = blockIdx.x;
  const float* src; u16* dst; int Ccols, dstStride, r0, c0;
  if (bid < 768) {
    const int sub = bid >> 8, rem = bid & 255;
    const int z = rem >> 4, y = rem & 15;
    src = (sub == 0 ? Wq : sub == 1 ? Wk : Wv) + (size_t)z * 65536;
    dst = WqkvT + (size_t)sub * 1024 * 1024 + (size_t)z * 65536;
    Ccols = 64; dstStride = 1024; r0 = y * 64; c0 = 0;
  } else if (bid < 1024) {
    const int rem = bid - 768, xx = rem & 15, y = rem >> 4;
    src = Wproj; dst = WprojT; Ccols = 1024; dstStride = 1024;
    r0 = y * 64; c0 = xx * 64;
  } else if (bid < 2048) {
    const int rem = bid - 1024, xx = rem & 63, y = rem >> 6;
    src = W1; dst = W1T; Ccols = 4096; dstStride = 1024;
    r0 = y * 64; c0 = xx * 64;
  } else {
    const int rem = bid - 2048, xx = rem & 15, y = rem >> 4;
    src = W2; dst = W2T; Ccols = 1024; dstStride = 4096;
    r0 = y * 64; c0 = xx * 64;
  }
  __shared__ float t[64][65];
  const int tr = threadIdx.x >> 4, tc4 = (threadIdx.x & 15) * 4;
#pragma unroll
  for (int p = 0; p < 4; ++p) {
    int r = p * 16 + tr;
    float4 v = *(const float4*)(src + (size_t)(r0 + r) * Ccols + c0 + tc4);
    t[r][tc4 + 0] = v.x; t[r][tc4 + 1] = v.y;
    t[r][tc4 + 2] = v.z; t[r][tc4 + 3] = v.w;
  }
  __syncthreads();
#pragma unroll
  for (int p = 0; p < 4; ++p) {
    int c = p * 16 + tr;
    uint2 pk;
    pk.x = (u32)f2bf(t[tc4 + 0][c]) | ((u32)f2bf(t[tc4 + 1][c]) << 16);
    pk.y = (u32)f2bf(t[tc4 + 2][c]) | ((u32)f2bf(t[tc4 + 3][c]) << 16);
    *(uint2*)(dst + (size_t)(c0 + c) * dstStride + r0 + tc4) = pk;
  }
}

// ---------------------------------------------------------------------------
// LayerNorm: one block per row of 1024 fp32; out bf16.
// ---------------------------------------------------------------------------
__global__ __launch_bounds__(256) void ln_kernel(
    const float* __restrict__ x, const float* __restrict__ g,
    const float* __restrict__ be, u16* __restrict__ out) {
  const int row = blockIdx.x, tid = threadIdx.x;
  const float* xr = x + (size_t)row * 1024;
  float4 v = *(const float4*)(xr + tid * 4);
  float s = v.x + v.y + v.z + v.w;
  float q = v.x * v.x + v.y * v.y + v.z * v.z + v.w * v.w;
#pragma unroll
  for (int off = 32; off > 0; off >>= 1) {
    s += __shfl_down(s, off);
    q += __shfl_down(q, off);
  }
  __shared__ float red[8];
  const int wid = tid >> 6, lane = tid & 63;
  if (lane == 0) { red[wid] = s; red[wid + 4] = q; }
  __syncthreads();
  s = red[0] + red[1] + red[2] + red[3];
  q = red[4] + red[5] + red[6] + red[7];
  const float mu = s * (1.f / 1024.f);
  const float var = q * (1.f / 1024.f) - mu * mu;
  const float rs = rsqrtf(var + 1e-5f);
  float4 gv = *(const float4*)(g + tid * 4);
  float4 bv = *(const float4*)(be + tid * 4);
  float o0 = (v.x - mu) * rs * gv.x + bv.x;
  float o1 = (v.y - mu) * rs * gv.y + bv.y;
  float o2 = (v.z - mu) * rs * gv.z + bv.z;
  float o3 = (v.w - mu) * rs * gv.w + bv.w;
  uint2 pk;
  pk.x = (u32)f2bf(o0) | ((u32)f2bf(o1) << 16);
  pk.y = (u32)f2bf(o2) | ((u32)f2bf(o3) << 16);
  *(uint2*)(out + (size_t)row * 1024 + tid * 4) = pk;
}

// ---------------------------------------------------------------------------
// combine: out = P0 + P1 + bias + resid  (fp32)
// ---------------------------------------------------------------------------
__global__ __launch_bounds__(256) void combine_kernel(
    const float* __restrict__ P, const float* __restrict__ resid,
    const float* __restrict__ bias, float* __restrict__ out) {
  const int row = blockIdx.x, c4 = threadIdx.x * 4;
  const size_t idx = (size_t)row * 1024 + c4;
  float4 p0 = *(const float4*)(P + idx);
  float4 p1 = *(const float4*)(P + 4194304 + idx);
  float4 r  = *(const float4*)(resid + idx);
  float4 bb = *(const float4*)(bias + c4);
  float4 o;
  o.x = p0.x + p1.x + r.x + bb.x;
  o.y = p0.y + p1.y + r.y + bb.y;
  o.z = p0.z + p1.z + r.z + bb.z;
  o.w = p0.w + p1.w + r.w + bb.w;
  *(float4*)(out + idx) = o;
}

// ---------------------------------------------------------------------------
// 256x256 8-phase GEMM (T3+T4+T5) — QKV + FF1.
// ---------------------------------------------------------------------------
template <int EPI>
__global__ __launch_bounds__(512, 2) void gemm256_kernel(
    const u16* __restrict__ A, const u16* __restrict__ BT,
    const float* __restrict__ bias, const float* __restrict__ resid,
    void* __restrict__ out, int M, int N, int K) {
  __shared__ u16 lds[2][2][256][64];  // 128 KiB
  const int tid = threadIdx.x;
  const int wid = tid >> 6, lane = tid & 63;
  const int m0 = blockIdx.y * 256, n0 = blockIdx.x * 256;
  const int wr = (wid >> 2) * 128;
  const int wc = (wid & 3) * 64;
  const int l15 = lane & 15, g = lane >> 4;
  const int lr = lane >> 3;
  const int cswz = ((lane & 7) * 8) ^ (lr << 3);
  const int swz = (l15 & 7) << 3;
  const u16* Abase = A + (size_t)m0 * K;
  const u16* Bbase = BT + (size_t)n0 * K;
  const int nkt = K >> 6;

  f32x4 acc[8][4] = {};
  s16x8 bf[4][2];

  auto issue_half = [&](const u16* Xbase, int xi, int t, int hf) {
    const int b = t & 1;
    const int r0 = hf * 128 + wid * 8;
    gload16(Xbase + (size_t)(r0 + lr) * K + t * 64 + cswz, &lds[b][xi][r0][0]);
    gload16(Xbase + (size_t)(r0 + 64 + lr) * K + t * 64 + cswz, &lds[b][xi][r0 + 64][0]);
  };

  issue_half(Abase, 0, 0, 0);
  issue_half(Abase, 0, 0, 1);
  issue_half(Bbase, 1, 0, 0);
  issue_half(Bbase, 1, 0, 1);
  asm volatile("s_waitcnt vmcnt(0)" ::: "memory");
  __builtin_amdgcn_s_barrier();

  for (int i = 0; i < nkt; i += 2) {
#pragma unroll
    for (int p = 0; p < 4; ++p) {
      s16x8 af[2][2];
#pragma unroll
      for (int q = 0; q < 2; ++q) {
        const int R = wr + (2 * p + q) * 16 + l15;
#pragma unroll
        for (int h = 0; h < 2; ++h)
          af[q][h] = *(const s16x8*)(&lds[0][0][R][(h * 32 + g * 8) ^ swz]);
      }
      if (p == 0) {
#pragma unroll
        for (int n = 0; n < 4; ++n) {
          const int R = wc + n * 16 + l15;
#pragma unroll
          for (int h = 0; h < 2; ++h)
            bf[n][h] = *(const s16x8*)(&lds[0][1][R][(h * 32 + g * 8) ^ swz]);
        }
      }
      if (i + 1 < nkt) {
        if (p == 0) issue_half(Abase, 0, i + 1, 0);
        else if (p == 1) issue_half(Abase, 0, i + 1, 1);
        else if (p == 2) issue_half(Bbase, 1, i + 1, 0);
        else issue_half(Bbase, 1, i + 1, 1);
      }
      __builtin_amdgcn_s_barrier();
      asm volatile("s_waitcnt lgkmcnt(0)" ::: "memory");
      __builtin_amdgcn_sched_barrier(0);
      __builtin_amdgcn_s_setprio(1);
#pragma unroll
      for (int q = 0; q < 2; ++q)
#pragma unroll
        for (int n = 0; n < 4; ++n) {
          acc[2 * p + q][n] = __builtin_amdgcn_mfma_f32_16x16x32_bf16(af[q][0], bf[n][0], acc[2 * p + q][n], 0, 0, 0);
          acc[2 * p + q][n] = __builtin_amdgcn_mfma_f32_16x16x32_bf16(af[q][1], bf[n][1], acc[2 * p + q][n], 0, 0, 0);
        }
      __builtin_amdgcn_s_setprio(0);
      if (p == 3)
        asm volatile("s_waitcnt vmcnt(0)" ::: "memory");
      __builtin_amdgcn_s_barrier();
    }
    if (i + 1 < nkt) {
#pragma unroll
      for (int p = 0; p < 4; ++p) {
        s16x8 af[2][2];
#pragma unroll
        for (int q = 0; q < 2; ++q) {
          const int R = wr + (2 * p + q) * 16 + l15;
#pragma unroll
          for (int h = 0; h < 2; ++h)
            af[q][h] = *(const s16x8*)(&lds[1][0][R][(h * 32 + g * 8) ^ swz]);
        }
        if (p == 0) {
#pragma unroll
          for (int n = 0; n < 4; ++n) {
            const int R = wc + n * 16 + l15;
#pragma unroll
            for (int h = 0; h < 2; ++h)
              bf[n][h] = *(const s16x8*)(&lds[1][1][R][(h * 32 + g * 8) ^ swz]);
          }
        }
        if (i + 2 < nkt) {
          if (p == 0) issue_half(Abase, 0, i + 2, 0);
          else if (p == 1) issue_half(Abase, 0, i + 2, 1);
          else if (p == 2) issue_half(Bbase, 1, i + 2, 0);
          else issue_half(Bbase, 1, i + 2, 1);
        }
        __builtin_amdgcn_s_barrier();
        asm volatile("s_waitcnt lgkmcnt(0)" ::: "memory");
        __builtin_amdgcn_sched_barrier(0);
        __builtin_amdgcn_s_setprio(1);
#pragma unroll
        for (int q = 0; q < 2; ++q)
#pragma unroll
          for (int n = 0; n < 4; ++n) {
            acc[2 * p + q][n] = __builtin_amdgcn_mfma_f32_16x16x32_bf16(af[q][0], bf[n][0], acc[2 * p + q][n], 0, 0, 0);
            acc[2 * p + q][n] = __builtin_amdgcn_mfma_f32_16x16x32_bf16(af[q][1], bf[n][1], acc[2 * p + q][n], 0, 0, 0);
          }
        __builtin_amdgcn_s_setprio(0);
        if (p == 3)
          asm volatile("s_waitcnt vmcnt(0)" ::: "memory");
        __builtin_amdgcn_s_barrier();
      }
    }
  }

#pragma unroll
  for (int mi = 0; mi < 8; ++mi)
#pragma unroll
    for (int n = 0; n < 4; ++n) {
      const int col = n0 + wc + n * 16 + l15;
      float bv = (EPI >= 1) ? bias[col] : 0.f;
#pragma unroll
      for (int ii = 0; ii < 4; ++ii) {
        const int row = m0 + wr + mi * 16 + g * 4 + ii;
        float v = acc[mi][n][ii];
        if (EPI >= 1) v += bv;
        if (EPI == 1) v = fmaxf(v, 0.f);
        ((u16*)out)[(size_t)row * N + col] = f2bf(v);
      }
    }
}

// ---------------------------------------------------------------------------
// gemm128d: 128x128 2-phase dbuf. EPI 2: +bias+resid -> fp32.
// EPI 3: split-K partial (blockIdx.z selects K-chunk + output slab).
// ---------------------------------------------------------------------------
template <int EPI>
__global__ __launch_bounds__(256, 2) void gemm128d_kernel(
    const u16* __restrict__ A, const u16* __restrict__ BT,
    const float* __restrict__ bias, const float* __restrict__ resid,
    void* __restrict__ out, int M, int N, int K, int lda) {
  __shared__ u16 lds[2][2][128][64];  // 64 KiB
  const int tid = threadIdx.x;
  const int wid = tid >> 6, lane = tid & 63;
  const int m0 = blockIdx.y * 128, n0 = blockIdx.x * 128;
  const int wr = (wid >> 1) * 64, wc = (wid & 1) * 64;
  const int l15 = lane & 15, g = lane >> 4;
  const int lr = lane >> 3;
  const int cswz = ((lane & 7) * 8) ^ (lr << 3);
  const int swz = (l15 & 7) << 3;
  const int nkt = K >> 6;
  f32x4 acc[4][4] = {};

  if (EPI == 3) {
    const int koff = (int)blockIdx.z * K;
    A += koff; BT += koff;
  }

  auto stage = [&](int bsel, int t) {
#pragma unroll
    for (int p = 0; p < 4; ++p) {
      const int row = (p * 4 + wid) * 8;
      gload16(A + (size_t)(m0 + row + lr) * lda + t * 64 + cswz, &lds[bsel][0][row][0]);
    }
#pragma unroll
    for (int p = 0; p < 4; ++p) {
      const int row = (p * 4 + wid) * 8;
      gload16(BT + (size_t)(n0 + row + lr) * lda + t * 64 + cswz, &lds[bsel][1][row][0]);
    }
  };

  stage(0, 0);
  __syncthreads();

  int cur = 0;
  for (int i = 0; i < nkt; ++i) {
    if (i + 1 < nkt) stage(cur ^ 1, i + 1);
    s16x8 af[4][2], bf[4][2];
#pragma unroll
    for (int m = 0; m < 4; ++m) {
      const int R = wr + m * 16 + l15;
#pragma unroll
      for (int h = 0; h < 2; ++h)
        af[m][h] = *(const s16x8*)(&lds[cur][0][R][(h * 32 + g * 8) ^ swz]);
    }
#pragma unroll
    for (int n = 0; n < 4; ++n) {
      const int R = wc + n * 16 + l15;
#pragma unroll
      for (int h = 0; h < 2; ++h)
        bf[n][h] = *(const s16x8*)(&lds[cur][1][R][(h * 32 + g * 8) ^ swz]);
    }
    __builtin_amdgcn_s_setprio(1);
#pragma unroll
    for (int m = 0; m < 4; ++m)
#pragma unroll
      for (int n = 0; n < 4; ++n) {
        acc[m][n] = __builtin_amdgcn_mfma_f32_16x16x32_bf16(af[m][0], bf[n][0], acc[m][n], 0, 0, 0);
        acc[m][n] = __builtin_amdgcn_mfma_f32_16x16x32_bf16(af[m][1], bf[n][1], acc[m][n], 0, 0, 0);
      }
    __builtin_amdgcn_s_setprio(0);
    __syncthreads();
    cur ^= 1;
  }

  float* outf = (float*)out;
  if (EPI == 3) outf += (size_t)blockIdx.z * M * N;
#pragma unroll
  for (int m = 0; m < 4; ++m) {
#pragma unroll
    for (int n = 0; n < 4; ++n) {
      const int col = n0 + wc + n * 16 + l15;
      float bv = (EPI == 1 || EPI == 2) ? bias[col] : 0.f;
#pragma unroll
      for (int i = 0; i < 4; ++i) {
        const int row = m0 + wr + m * 16 + g * 4 + i;
        float v = acc[m][n][i];
        if (EPI == 1 || EPI == 2) v += bv;
        if (EPI == 1) v = fmaxf(v, 0.f);
        if (EPI == 2) {
          v += resid[(size_t)row * N + col];
          outf[(size_t)row * N + col] = v;
        } else if (EPI == 3) {
          outf[(size_t)row * N + col] = v;
        } else {
          ((u16*)out)[(size_t)row * N + col] = f2bf(v);
        }
      }
    }
  }
}

// ---------------------------------------------------------------------------
// MFMA causal flash attention with split-KV. 8 waves, QBLK=128, K/V dbuf,
// one barrier/tile. Grid 768 = 24 slots x 32 bh (lid = slot*32 + bh):
//   slot<8:  qb=slot, full KV range, direct output.
//   slot>=8: idx=slot-8; qb=8+(idx>>1); half=idx&1; KV tiles
//            [half?qb+1:0, half?2qb+2:qb+1); writes raw partials
//            (O in local m-frame, reduced l, uniform m) to scratch.
// All 768 blocks co-resident (3/CU). T13 defer-max; T14 reg-prefetch.
// ---------------------------------------------------------------------------
__global__ __launch_bounds__(512) void attn_split_kernel(
    const u16* __restrict__ qkv, u16* __restrict__ o,
    float* __restrict__ Opart, float* __restrict__ mpart,
    float* __restrict__ lpart) {
  __shared__ u16 sK[2][64][72];   // [buf][s][d]
  __shared__ u16 sVt[2][64][68];  // [buf][d][s]
  __shared__ u16 sP[8][16][72];   // per-wave P strip
  const int tid = threadIdx.x;
  const int lid = (int)blockIdx.x;
  const int bh = lid & 31, slot = lid >> 5;
  const int b = bh >> 4, h = bh & 15;
  int qb, t0, t1, half = 0; bool split;
  if (slot < 8) { qb = slot; t0 = 0; t1 = 2 * qb + 2; split = false; }
  else {
    const int idx = slot - 8;
    qb = 8 + (idx >> 1); half = idx & 1;
    const int ntt = 2 * qb + 2, hlen = ntt >> 1;
    t0 = half ? hlen : 0; t1 = half ? ntt : hlen; split = true;
  }
  const int w = tid >> 6, lane = tid & 63;
  const int l15 = lane & 15, g = lane >> 4;
  const float c = 0.125f * 1.4426950408889634f;  // scale * log2(e)
  const int ks_r = tid >> 3, ks_c = (tid & 7) * 8;   // K: 512 x 16B
  const int vs_s = tid & 63, vs_d = (tid >> 6) * 8;  // V^T: 512 x 8 u16
  const u16* kbase = qkv + (size_t)(b * 2048) * 3072 + 1024 + h * 64;
  const u16* vbase = kbase + 1024;
  const int qw = qb * 128 + w * 16;  // wave q base

  const size_t qrow = (size_t)(b * 2048 + qw + l15);
  s16x8 qf0 = *(const s16x8*)(qkv + qrow * 3072 + h * 64 + g * 8);
  s16x8 qf1 = *(const s16x8*)(qkv + qrow * 3072 + h * 64 + 32 + g * 8);

  f32x4 oacc[4] = {};
  float mrow[4] = {-1e30f, -1e30f, -1e30f, -1e30f};
  float lrow[4] = {0.f, 0.f, 0.f, 0.f};  // per-lane partial; reduced at end

  uint4 kr0, vr0;
  {
    const u16* kp = kbase + (size_t)(t0 * 64 + ks_r) * 3072 + ks_c;
    kr0 = *(const uint4*)kp;
    const u16* vp = vbase + (size_t)(t0 * 64 + vs_s) * 3072 + vs_d;
    vr0 = *(const uint4*)vp;
  }
  for (int t = t0; t < t1; ++t) {
    const int pb = t & 1;
    *(uint4*)(&sK[pb][ks_r][ks_c]) = kr0;
    {
      union { uint4 q4; u16 e[8]; } va;
      va.q4 = vr0;
#pragma unroll
      for (int j = 0; j < 8; ++j) sVt[pb][vs_d + j][vs_s] = va.e[j];
    }
    if (t + 1 < t1) {  // T14: issue next tile's global loads
      const u16* kp = kbase + (size_t)((t + 1) * 64 + ks_r) * 3072 + ks_c;
      kr0 = *(const uint4*)kp;
      const u16* vp = vbase + (size_t)((t + 1) * 64 + vs_s) * 3072 + vs_d;
      vr0 = *(const uint4*)vp;
    }
    __syncthreads();  // buf[pb] visible; ONLY barrier this tile

    f32x4 st[4];
#pragma unroll
    for (int n = 0; n < 4; ++n) {
      s16x8 k0 = *(const s16x8*)(&sK[pb][n * 16 + l15][g * 8]);
      s16x8 k1 = *(const s16x8*)(&sK[pb][n * 16 + l15][32 + g * 8]);
      f32x4 a = {};
      a = __builtin_amdgcn_mfma_f32_16x16x32_bf16(qf0, k0, a, 0, 0, 0);
      a = __builtin_amdgcn_mfma_f32_16x16x32_bf16(qf1, k1, a, 0, 0, 0);
      st[n] = a;
    }
    if (t >= 2 * qb) {  // diagonal tiles (only reachable in second halves)
#pragma unroll
      for (int n = 0; n < 4; ++n)
#pragma unroll
        for (int i = 0; i < 4; ++i) {
          const int s_abs = t * 64 + n * 16 + l15;
          const int q_abs = qw + 4 * g + i;
          if (s_abs > q_abs) st[n][i] = -1e30f;
        }
    }
    float pm[4];
#pragma unroll
    for (int i = 0; i < 4; ++i)
      pm[i] = fmaxf(fmaxf(st[0][i], st[1][i]), fmaxf(st[2][i], st[3][i]));
#pragma unroll
    for (int msk = 1; msk < 16; msk <<= 1)
#pragma unroll
      for (int i = 0; i < 4; ++i) pm[i] = fmaxf(pm[i], __shfl_xor(pm[i], msk));
    bool need = false;  // T13 defer-max
#pragma unroll
    for (int i = 0; i < 4; ++i) need = need || (pm[i] > mrow[i] + 12.f);
    if (__any(need)) {
#pragma unroll
      for (int i = 0; i < 4; ++i) {
        const float mnew = fmaxf(mrow[i], pm[i]);
        const float corr = exp2f((mrow[i] - mnew) * c);
        mrow[i] = mnew;
        lrow[i] *= corr;
#pragma unroll
        for (int dt = 0; dt < 4; ++dt) oacc[dt][i] *= corr;
      }
    }
    float p[4][4];
#pragma unroll
    for (int n = 0; n < 4; ++n)
#pragma unroll
      for (int i = 0; i < 4; ++i) p[n][i] = exp2f((st[n][i] - mrow[i]) * c);
#pragma unroll
    for (int i = 0; i < 4; ++i)
      lrow[i] += (p[0][i] + p[1][i]) + (p[2][i] + p[3][i]);
#pragma unroll
    for (int n = 0; n < 4; ++n)
#pragma unroll
      for (int i = 0; i < 4; ++i)
        sP[w][4 * g + i][n * 16 + l15] = f2bf(p[n][i]);
    s16x8 pf0 = *(const s16x8*)(&sP[w][l15][g * 8]);
    s16x8 pf1 = *(const s16x8*)(&sP[w][l15][32 + g * 8]);
#pragma unroll
    for (int dt = 0; dt < 4; ++dt) {
      s16x8 vf0 = ld_s16x8_a8(&sVt[pb][dt * 16 + l15][g * 8]);
      s16x8 vf1 = ld_s16x8_a8(&sVt[pb][dt * 16 + l15][32 + g * 8]);
      oacc[dt] = __builtin_amdgcn_mfma_f32_16x16x32_bf16(pf0, vf0, oacc[dt], 0, 0, 0);
      oacc[dt] = __builtin_amdgcn_mfma_f32_16x16x32_bf16(pf1, vf1, oacc[dt], 0, 0, 0);
    }
  }

  // reduce lrow across the 16-lane group (all lanes end with the sum)
#pragma unroll
  for (int msk = 1; msk < 16; msk <<= 1)
#pragma unroll
    for (int i = 0; i < 4; ++i) lrow[i] += __shfl_xor(lrow[i], msk);

  if (!split) {
    float inv[4];
#pragma unroll
    for (int i = 0; i < 4; ++i) inv[i] = 1.f / lrow[i];
#pragma unroll
    for (int dt = 0; dt < 4; ++dt)
#pragma unroll
      for (int i = 0; i < 4; ++i) {
        const size_t row = (size_t)(b * 2048 + qw + 4 * g + i);
        o[row * 1024 + h * 64 + dt * 16 + l15] = f2bf(oacc[dt][i] * inv[i]);
      }
  } else {
    // partial slot p: 512 slots = (bh*8 + (qb-8))*2 + half
    const int pslot = (bh * 8 + (qb - 8)) * 2 + half;
    float* Ob = Opart + ((size_t)pslot * 128) * 64;
#pragma unroll
    for (int dt = 0; dt < 4; ++dt)
#pragma unroll
      for (int i = 0; i < 4; ++i) {
        const int lrw = w * 16 + 4 * g + i;  // local row in [0,128)
        Ob[(size_t)lrw * 64 + dt * 16 + l15] = oacc[dt][i];
      }
    if (l15 == 0) {
#pragma unroll
      for (int i = 0; i < 4; ++i) {
        const int lrw = w * 16 + 4 * g + i;
        mpart[pslot * 128 + lrw] = mrow[i];
        lpart[pslot * 128 + lrw] = lrow[i];
      }
    }
  }
}

// ---------------------------------------------------------------------------
// attn merge: combine the two half-KV partials for qb>=8 and write obuf.
// grid 256 = bh*8 + j (qb = 8+j), 256 threads: thread -> row tid>>1,
// cols (tid&1)*32..+32.
// ---------------------------------------------------------------------------
__global__ __launch_bounds__(256) void attn_merge_kernel(
    const float* __restrict__ Opart, const float* __restrict__ mpart,
    const float* __restrict__ lpart, u16* __restrict__ o) {
  const int bid = blockIdx.x;
  const int bh = bid >> 3, j = bid & 7;
  const int b = bh >> 4, h = bh & 15;
  const int qb = 8 + j;
  const int tid = threadIdx.x;
  const int r = tid >> 1, c0 = (tid & 1) * 32;
  const float c = 0.125f * 1.4426950408889634f;
  const int p0 = (bh * 8 + j) * 2, p1 = p0 + 1;
  const float m0 = mpart[p0 * 128 + r], m1 = mpart[p1 * 128 + r];
  const float l0 = lpart[p0 * 128 + r], l1 = lpart[p1 * 128 + r];
  const float mM = fmaxf(m0, m1);
  const float w0 = exp2f((m0 - mM) * c), w1 = exp2f((m1 - mM) * c);
  const float inv = 1.f / (l0 * w0 + l1 * w1);
  const float* O0 = Opart + ((size_t)p0 * 128 + r) * 64 + c0;
  const float* O1 = Opart + ((size_t)p1 * 128 + r) * 64 + c0;
  u16* op = o + (size_t)(b * 2048 + qb * 128 + r) * 1024 + h * 64 + c0;
#pragma unroll
  for (int k = 0; k < 32; k += 4) {
    float4 a = *(const float4*)(O0 + k);
    float4 bb = *(const float4*)(O1 + k);
    uint2 pk;
    pk.x = (u32)f2bf((a.x * w0 + bb.x * w1) * inv) |
           ((u32)f2bf((a.y * w0 + bb.y * w1) * inv) << 16);
    pk.y = (u32)f2bf((a.z * w0 + bb.z * w1) * inv) |
           ((u32)f2bf((a.w * w0 + bb.w * w1) * inv) << 16);
    *(uint2*)(op + k) = pk;
  }
}

// ---------------------------------------------------------------------------
extern "C" void kernel_launch(void* const* d_in, const int* in_sizes, int n_in,
                              void* d_out, int out_size, void* d_ws, size_t ws_size,
                              hipStream_t stream) {
  const float* x     = (const float*)d_in[0];
  const float* Wq    = (const float*)d_in[1];
  const float* Wk    = (const float*)d_in[2];
  const float* Wv    = (const float*)d_in[3];
  const float* Wproj = (const float*)d_in[4];
  const float* bproj = (const float*)d_in[5];
  const float* W1    = (const float*)d_in[6];
  const float* b1    = (const float*)d_in[7];
  const float* W2    = (const float*)d_in[8];
  const float* b2    = (const float*)d_in[9];
  const float* g1    = (const float*)d_in[10];
  const float* be1   = (const float*)d_in[11];
  const float* g2    = (const float*)d_in[12];
  const float* be2   = (const float*)d_in[13];
  float* out = (float*)d_out;

  u16* WqkvT  = (u16*)d_ws;                    // [3072][1024] bf16
  u16* WprojT = WqkvT + (size_t)3072 * 1024;   // [1024][1024]
  u16* W1T    = WprojT + (size_t)1024 * 1024;  // [4096][1024]
  u16* W2T    = W1T + (size_t)4096 * 1024;     // [1024][4096]
  u16* hbuf   = W2T + (size_t)1024 * 4096;     // [4096][1024]
  u16* qkv    = hbuf + (size_t)4096 * 1024;    // [4096][3072]
  u16* obuf   = qkv + (size_t)4096 * 3072;     // [4096][1024]
  float* x2   = (float*)(obuf + (size_t)4096 * 1024);  // [4096][1024] fp32
  u16* a1     = (u16*)(x2 + (size_t)4096 * 1024);      // [4096][4096]
  float* Pk   = (float*)hbuf;  // FF2 split-K partials (32 MB over hbuf+qkv)
  // attn split-KV partials live in the a1 region (dead during attn; FF1
  // writes a1 only after the merge has consumed these).
  float* Opart = (float*)a1;                       // [512][128][64] fp32
  float* mpart = Opart + (size_t)512 * 128 * 64;   // [512][128]
  float* lpart = mpart + (size_t)512 * 128;        // [512][128]

  transpose_all_kernel<<<3072, 256, 0, stream>>>(Wq, Wk, Wv, Wproj, W1, W2,
                                                 WqkvT, WprojT, W1T, W2T);
  ln_kernel<<<4096, 256, 0, stream>>>(x, g1, be1, hbuf);
  gemm256_kernel<0><<<dim3(12, 16), 512, 0, stream>>>(hbuf, WqkvT, nullptr, nullptr, qkv, 4096, 3072, 1024);
  attn_split_kernel<<<768, 512, 0, stream>>>(qkv, obuf, Opart, mpart, lpart);
  attn_merge_kernel<<<256, 256, 0, stream>>>(Opart, mpart, lpart, obuf);
  gemm128d_kernel<2><<<dim3(8, 32), 256, 0, stream>>>(obuf, WprojT, bproj, x, x2, 4096, 1024, 1024, 1024);
  ln_kernel<<<4096, 256, 0, stream>>>(x2, g2, be2, hbuf);
  gemm256_kernel<1><<<dim3(16, 16), 512, 0, stream>>>(hbuf, W1T, b1, nullptr, a1, 4096, 4096, 1024);
  gemm128d_kernel<3><<<dim3(8, 32, 2), 256, 0, stream>>>(a1, W2T, nullptr, nullptr, Pk, 4096, 1024, 2048, 4096);
  combine_kernel<<<4096, 256, 0, stream>>>(Pk, x2, b2, out);
}

// Round 22
// 236.109 us; speedup vs baseline: 1.0595x; 1.0595x over previous
//
#include <hip/hip_runtime.h>
#include <stdint.h>

// Round 22 == round 20 kernel (best measured: 236.3 us, absmax 0.03125).
// Round 21's split-KV attn REGRESSED (75.9 + merge vs 69.3): tile count is
// conserved and 3 blocks/CU did not raise per-CU tile throughput => attn is
// per-CU pipe-throughput-bound, not latency-wall-bound; the split only added
// partial/merge overhead. Reverting to r20 and freezing.

typedef unsigned short u16;
typedef unsigned int u32;
typedef __attribute__((ext_vector_type(4))) float f32x4;
typedef __attribute__((ext_vector_type(8))) short s16x8;

__device__ __forceinline__ u16 f2bf(float f) {
  u32 u = __builtin_bit_cast(u32, f);
  u += 0x7fffu + ((u >> 16) & 1u);
  return (u16)(u >> 16);
}
__device__ __forceinline__ s16x8 ld_s16x8_a8(const u16* p) {
  union { uint2 d[2]; s16x8 v; } u;
  u.d[0] = *(const uint2*)p;
  u.d[1] = *(const uint2*)(p + 4);
  return u.v;
}
__device__ __forceinline__ void gload16(const u16* g, u16* lds_base) {
  __builtin_amdgcn_global_load_lds(
      (const __attribute__((address_space(1))) void*)g,
      (__attribute__((address_space(3))) void*)lds_base, 16, 0, 0);
}

// ---------------------------------------------------------------------------
// Fused weight transposes fp32 -> bf16^T, one launch, 3072 blocks.
// ---------------------------------------------------------------------------
__global__ __launch_bounds__(256) void transpose_all_kernel(
    const float* __restrict__ Wq, const float* __restrict__ Wk,
    const float* __restrict__ Wv, const float* __restrict__ Wproj,
    const float* __restrict__ W1, const float* __restrict__ W2,
    u16* __restrict__ WqkvT, u16* __restrict__ WprojT,
    u16* __restrict__ W1T, u16* __restrict__ W2T) {
  const int bid = blockIdx.x;
  const float* src; u16* dst; int Ccols, dstStride, r0, c0;
  if (bid < 768) {
    const int sub = bid >> 8, rem = bid & 255;
    const int z = rem >> 4, y = rem & 15;
    src = (sub == 0 ? Wq : sub == 1 ? Wk : Wv) + (size_t)z * 65536;
    dst = WqkvT + (size_t)sub * 1024 * 1024 + (size_t)z * 65536;
    Ccols = 64; dstStride = 1024; r0 = y * 64; c0 = 0;
  } else if (bid < 1024) {
    const int rem = bid - 768, xx = rem & 15, y = rem >> 4;
    src = Wproj; dst = WprojT; Ccols = 1024; dstStride = 1024;
    r0 = y * 64; c0 = xx * 64;
  } else if (bid < 2048) {
    const int rem = bid - 1024, xx = rem & 63, y = rem >> 6;
    src = W1; dst = W1T; Ccols = 4096; dstStride = 1024;
    r0 = y * 64; c0 = xx * 64;
  } else {
    const int rem = bid - 2048, xx = rem & 15, y = rem >> 4;
    src = W2; dst = W2T; Ccols = 1024; dstStride = 4096;
    r0 = y * 64; c0 = xx * 64;
  }
  __shared__ float t[64][65];
  const int tr = threadIdx.x >> 4, tc4 = (threadIdx.x & 15) * 4;
#pragma unroll
  for (int p = 0; p < 4; ++p) {
    int r = p * 16 + tr;
    float4 v = *(const float4*)(src + (size_t)(r0 + r) * Ccols + c0 + tc4);
    t[r][tc4 + 0] = v.x; t[r][tc4 + 1] = v.y;
    t[r][tc4 + 2] = v.z; t[r][tc4 + 3] = v.w;
  }
  __syncthreads();
#pragma unroll
  for (int p = 0; p < 4; ++p) {
    int c = p * 16 + tr;
    uint2 pk;
    pk.x = (u32)f2bf(t[tc4 + 0][c]) | ((u32)f2bf(t[tc4 + 1][c]) << 16);
    pk.y = (u32)f2bf(t[tc4 + 2][c]) | ((u32)f2bf(t[tc4 + 3][c]) << 16);
    *(uint2*)(dst + (size_t)(c0 + c) * dstStride + r0 + tc4) = pk;
  }
}

// ---------------------------------------------------------------------------
// LayerNorm: one block per row of 1024 fp32; out bf16.
// ---------------------------------------------------------------------------
__global__ __launch_bounds__(256) void ln_kernel(
    const float* __restrict__ x, const float* __restrict__ g,
    const float* __restrict__ be, u16* __restrict__ out) {
  const int row = blockIdx.x, tid = threadIdx.x;
  const float* xr = x + (size_t)row * 1024;
  float4 v = *(const float4*)(xr + tid * 4);
  float s = v.x + v.y + v.z + v.w;
  float q = v.x * v.x + v.y * v.y + v.z * v.z + v.w * v.w;
#pragma unroll
  for (int off = 32; off > 0; off >>= 1) {
    s += __shfl_down(s, off);
    q += __shfl_down(q, off);
  }
  __shared__ float red[8];
  const int wid = tid >> 6, lane = tid & 63;
  if (lane == 0) { red[wid] = s; red[wid + 4] = q; }
  __syncthreads();
  s = red[0] + red[1] + red[2] + red[3];
  q = red[4] + red[5] + red[6] + red[7];
  const float mu = s * (1.f / 1024.f);
  const float var = q * (1.f / 1024.f) - mu * mu;
  const float rs = rsqrtf(var + 1e-5f);
  float4 gv = *(const float4*)(g + tid * 4);
  float4 bv = *(const float4*)(be + tid * 4);
  float o0 = (v.x - mu) * rs * gv.x + bv.x;
  float o1 = (v.y - mu) * rs * gv.y + bv.y;
  float o2 = (v.z - mu) * rs * gv.z + bv.z;
  float o3 = (v.w - mu) * rs * gv.w + bv.w;
  uint2 pk;
  pk.x = (u32)f2bf(o0) | ((u32)f2bf(o1) << 16);
  pk.y = (u32)f2bf(o2) | ((u32)f2bf(o3) << 16);
  *(uint2*)(out + (size_t)row * 1024 + tid * 4) = pk;
}

// ---------------------------------------------------------------------------
// combine: out = P0 + P1 + bias + resid  (fp32)
// ---------------------------------------------------------------------------
__global__ __launch_bounds__(256) void combine_kernel(
    const float* __restrict__ P, const float* __restrict__ resid,
    const float* __restrict__ bias, float* __restrict__ out) {
  const int row = blockIdx.x, c4 = threadIdx.x * 4;
  const size_t idx = (size_t)row * 1024 + c4;
  float4 p0 = *(const float4*)(P + idx);
  float4 p1 = *(const float4*)(P + 4194304 + idx);
  float4 r  = *(const float4*)(resid + idx);
  float4 bb = *(const float4*)(bias + c4);
  float4 o;
  o.x = p0.x + p1.x + r.x + bb.x;
  o.y = p0.y + p1.y + r.y + bb.y;
  o.z = p0.z + p1.z + r.z + bb.z;
  o.w = p0.w + p1.w + r.w + bb.w;
  *(float4*)(out + idx) = o;
}

// ---------------------------------------------------------------------------
// 256x256 8-phase GEMM (T3+T4+T5) — QKV + FF1.
// ---------------------------------------------------------------------------
template <int EPI>
__global__ __launch_bounds__(512, 2) void gemm256_kernel(
    const u16* __restrict__ A, const u16* __restrict__ BT,
    const float* __restrict__ bias, const float* __restrict__ resid,
    void* __restrict__ out, int M, int N, int K) {
  __shared__ u16 lds[2][2][256][64];  // 128 KiB
  const int tid = threadIdx.x;
  const int wid = tid >> 6, lane = tid & 63;
  const int m0 = blockIdx.y * 256, n0 = blockIdx.x * 256;
  const int wr = (wid >> 2) * 128;
  const int wc = (wid & 3) * 64;
  const int l15 = lane & 15, g = lane >> 4;
  const int lr = lane >> 3;
  const int cswz = ((lane & 7) * 8) ^ (lr << 3);
  const int swz = (l15 & 7) << 3;
  const u16* Abase = A + (size_t)m0 * K;
  const u16* Bbase = BT + (size_t)n0 * K;
  const int nkt = K >> 6;

  f32x4 acc[8][4] = {};
  s16x8 bf[4][2];

  auto issue_half = [&](const u16* Xbase, int xi, int t, int hf) {
    const int b = t & 1;
    const int r0 = hf * 128 + wid * 8;
    gload16(Xbase + (size_t)(r0 + lr) * K + t * 64 + cswz, &lds[b][xi][r0][0]);
    gload16(Xbase + (size_t)(r0 + 64 + lr) * K + t * 64 + cswz, &lds[b][xi][r0 + 64][0]);
  };

  issue_half(Abase, 0, 0, 0);
  issue_half(Abase, 0, 0, 1);
  issue_half(Bbase, 1, 0, 0);
  issue_half(Bbase, 1, 0, 1);
  asm volatile("s_waitcnt vmcnt(0)" ::: "memory");
  __builtin_amdgcn_s_barrier();

  for (int i = 0; i < nkt; i += 2) {
#pragma unroll
    for (int p = 0; p < 4; ++p) {
      s16x8 af[2][2];
#pragma unroll
      for (int q = 0; q < 2; ++q) {
        const int R = wr + (2 * p + q) * 16 + l15;
#pragma unroll
        for (int h = 0; h < 2; ++h)
          af[q][h] = *(const s16x8*)(&lds[0][0][R][(h * 32 + g * 8) ^ swz]);
      }
      if (p == 0) {
#pragma unroll
        for (int n = 0; n < 4; ++n) {
          const int R = wc + n * 16 + l15;
#pragma unroll
          for (int h = 0; h < 2; ++h)
            bf[n][h] = *(const s16x8*)(&lds[0][1][R][(h * 32 + g * 8) ^ swz]);
        }
      }
      if (i + 1 < nkt) {
        if (p == 0) issue_half(Abase, 0, i + 1, 0);
        else if (p == 1) issue_half(Abase, 0, i + 1, 1);
        else if (p == 2) issue_half(Bbase, 1, i + 1, 0);
        else issue_half(Bbase, 1, i + 1, 1);
      }
      __builtin_amdgcn_s_barrier();
      asm volatile("s_waitcnt lgkmcnt(0)" ::: "memory");
      __builtin_amdgcn_sched_barrier(0);
      __builtin_amdgcn_s_setprio(1);
#pragma unroll
      for (int q = 0; q < 2; ++q)
#pragma unroll
        for (int n = 0; n < 4; ++n) {
          acc[2 * p + q][n] = __builtin_amdgcn_mfma_f32_16x16x32_bf16(af[q][0], bf[n][0], acc[2 * p + q][n], 0, 0, 0);
          acc[2 * p + q][n] = __builtin_amdgcn_mfma_f32_16x16x32_bf16(af[q][1], bf[n][1], acc[2 * p + q][n], 0, 0, 0);
        }
      __builtin_amdgcn_s_setprio(0);
      if (p == 3)
        asm volatile("s_waitcnt vmcnt(0)" ::: "memory");
      __builtin_amdgcn_s_barrier();
    }
    if (i + 1 < nkt) {
#pragma unroll
      for (int p = 0; p < 4; ++p) {
        s16x8 af[2][2];
#pragma unroll
        for (int q = 0; q < 2; ++q) {
          const int R = wr + (2 * p + q) * 16 + l15;
#pragma unroll
          for (int h = 0; h < 2; ++h)
            af[q][h] = *(const s16x8*)(&lds[1][0][R][(h * 32 + g * 8) ^ swz]);
        }
        if (p == 0) {
#pragma unroll
          for (int n = 0; n < 4; ++n) {
            const int R = wc + n * 16 + l15;
#pragma unroll
            for (int h = 0; h < 2; ++h)
              bf[n][h] = *(const s16x8*)(&lds[1][1][R][(h * 32 + g * 8) ^ swz]);
          }
        }
        if (i + 2 < nkt) {
          if (p == 0) issue_half(Abase, 0, i + 2, 0);
          else if (p == 1) issue_half(Abase, 0, i + 2, 1);
          else if (p == 2) issue_half(Bbase, 1, i + 2, 0);
          else issue_half(Bbase, 1, i + 2, 1);
        }
        __builtin_amdgcn_s_barrier();
        asm volatile("s_waitcnt lgkmcnt(0)" ::: "memory");
        __builtin_amdgcn_sched_barrier(0);
        __builtin_amdgcn_s_setprio(1);
#pragma unroll
        for (int q = 0; q < 2; ++q)
#pragma unroll
          for (int n = 0; n < 4; ++n) {
            acc[2 * p + q][n] = __builtin_amdgcn_mfma_f32_16x16x32_bf16(af[q][0], bf[n][0], acc[2 * p + q][n], 0, 0, 0);
            acc[2 * p + q][n] = __builtin_amdgcn_mfma_f32_16x16x32_bf16(af[q][1], bf[n][1], acc[2 * p + q][n], 0, 0, 0);
          }
        __builtin_amdgcn_s_setprio(0);
        if (p == 3)
          asm volatile("s_waitcnt vmcnt(0)" ::: "memory");
        __builtin_amdgcn_s_barrier();
      }
    }
  }

#pragma unroll
  for (int mi = 0; mi < 8; ++mi)
#pragma unroll
    for (int n = 0; n < 4; ++n) {
      const int col = n0 + wc + n * 16 + l15;
      float bv = (EPI >= 1) ? bias[col] : 0.f;
#pragma unroll
      for (int ii = 0; ii < 4; ++ii) {
        const int row = m0 + wr + mi * 16 + g * 4 + ii;
        float v = acc[mi][n][ii];
        if (EPI >= 1) v += bv;
        if (EPI == 1) v = fmaxf(v, 0.f);
        ((u16*)out)[(size_t)row * N + col] = f2bf(v);
      }
    }
}

// ---------------------------------------------------------------------------
// gemm128d: 128x128 2-phase dbuf. EPI 2: +bias+resid -> fp32.
// EPI 3: split-K partial (blockIdx.z selects K-chunk + output slab).
// ---------------------------------------------------------------------------
template <int EPI>
__global__ __launch_bounds__(256, 2) void gemm128d_kernel(
    const u16* __restrict__ A, const u16* __restrict__ BT,
    const float* __restrict__ bias, const float* __restrict__ resid,
    void* __restrict__ out, int M, int N, int K, int lda) {
  __shared__ u16 lds[2][2][128][64];  // 64 KiB
  const int tid = threadIdx.x;
  const int wid = tid >> 6, lane = tid & 63;
  const int m0 = blockIdx.y * 128, n0 = blockIdx.x * 128;
  const int wr = (wid >> 1) * 64, wc = (wid & 1) * 64;
  const int l15 = lane & 15, g = lane >> 4;
  const int lr = lane >> 3;
  const int cswz = ((lane & 7) * 8) ^ (lr << 3);
  const int swz = (l15 & 7) << 3;
  const int nkt = K >> 6;
  f32x4 acc[4][4] = {};

  if (EPI == 3) {
    const int koff = (int)blockIdx.z * K;
    A += koff; BT += koff;
  }

  auto stage = [&](int bsel, int t) {
#pragma unroll
    for (int p = 0; p < 4; ++p) {
      const int row = (p * 4 + wid) * 8;
      gload16(A + (size_t)(m0 + row + lr) * lda + t * 64 + cswz, &lds[bsel][0][row][0]);
    }
#pragma unroll
    for (int p = 0; p < 4; ++p) {
      const int row = (p * 4 + wid) * 8;
      gload16(BT + (size_t)(n0 + row + lr) * lda + t * 64 + cswz, &lds[bsel][1][row][0]);
    }
  };

  stage(0, 0);
  __syncthreads();

  int cur = 0;
  for (int i = 0; i < nkt; ++i) {
    if (i + 1 < nkt) stage(cur ^ 1, i + 1);
    s16x8 af[4][2], bf[4][2];
#pragma unroll
    for (int m = 0; m < 4; ++m) {
      const int R = wr + m * 16 + l15;
#pragma unroll
      for (int h = 0; h < 2; ++h)
        af[m][h] = *(const s16x8*)(&lds[cur][0][R][(h * 32 + g * 8) ^ swz]);
    }
#pragma unroll
    for (int n = 0; n < 4; ++n) {
      const int R = wc + n * 16 + l15;
#pragma unroll
      for (int h = 0; h < 2; ++h)
        bf[n][h] = *(const s16x8*)(&lds[cur][1][R][(h * 32 + g * 8) ^ swz]);
    }
    __builtin_amdgcn_s_setprio(1);
#pragma unroll
    for (int m = 0; m < 4; ++m)
#pragma unroll
      for (int n = 0; n < 4; ++n) {
        acc[m][n] = __builtin_amdgcn_mfma_f32_16x16x32_bf16(af[m][0], bf[n][0], acc[m][n], 0, 0, 0);
        acc[m][n] = __builtin_amdgcn_mfma_f32_16x16x32_bf16(af[m][1], bf[n][1], acc[m][n], 0, 0, 0);
      }
    __builtin_amdgcn_s_setprio(0);
    __syncthreads();
    cur ^= 1;
  }

  float* outf = (float*)out;
  if (EPI == 3) outf += (size_t)blockIdx.z * M * N;
#pragma unroll
  for (int m = 0; m < 4; ++m) {
#pragma unroll
    for (int n = 0; n < 4; ++n) {
      const int col = n0 + wc + n * 16 + l15;
      float bv = (EPI == 1 || EPI == 2) ? bias[col] : 0.f;
#pragma unroll
      for (int i = 0; i < 4; ++i) {
        const int row = m0 + wr + m * 16 + g * 4 + i;
        float v = acc[m][n][i];
        if (EPI == 1 || EPI == 2) v += bv;
        if (EPI == 1) v = fmaxf(v, 0.f);
        if (EPI == 2) {
          v += resid[(size_t)row * N + col];
          outf[(size_t)row * N + col] = v;
        } else if (EPI == 3) {
          outf[(size_t)row * N + col] = v;
        } else {
          ((u16*)out)[(size_t)row * N + col] = f2bf(v);
        }
      }
    }
  }
}

// ---------------------------------------------------------------------------
// MFMA causal flash attention, 8-wave QBLK=128, K/V dbuf, one barrier/tile.
// 1-D grid of 512 blocks (2/CU): lid<256 -> qb=15-((lid>>5)&7) (heavy),
// lid>=256 -> qb=(lid-256)>>5 (light, anti-correlated on the same CU);
// bh=lid&31. T13 defer-max; T14 reg-prefetch.
// ---------------------------------------------------------------------------
__global__ __launch_bounds__(512) void attn_mfma_kernel(
    const u16* __restrict__ qkv, u16* __restrict__ o) {
  __shared__ u16 sK[2][64][72];   // [buf][s][d]
  __shared__ u16 sVt[2][64][68];  // [buf][d][s]
  __shared__ u16 sP[8][16][72];   // per-wave P strip
  const int tid = threadIdx.x;
  const int lid = (int)blockIdx.x;
  const int bh = lid & 31;
  const int qb = (lid < 256) ? (15 - ((lid >> 5) & 7)) : ((lid - 256) >> 5);
  const int b = bh >> 4, h = bh & 15;
  const int w = tid >> 6, lane = tid & 63;
  const int l15 = lane & 15, g = lane >> 4;
  const float c = 0.125f * 1.4426950408889634f;  // scale * log2(e)
  const int ks_r = tid >> 3, ks_c = (tid & 7) * 8;   // K: 512 x 16B
  const int vs_s = tid & 63, vs_d = (tid >> 6) * 8;  // V^T: 512 x 8 u16
  const u16* kbase = qkv + (size_t)(b * 2048) * 3072 + 1024 + h * 64;
  const u16* vbase = kbase + 1024;
  const int qw = qb * 128 + w * 16;  // wave q base

  const size_t qrow = (size_t)(b * 2048 + qw + l15);
  s16x8 qf0 = *(const s16x8*)(qkv + qrow * 3072 + h * 64 + g * 8);
  s16x8 qf1 = *(const s16x8*)(qkv + qrow * 3072 + h * 64 + 32 + g * 8);

  f32x4 oacc[4] = {};
  float mrow[4] = {-1e30f, -1e30f, -1e30f, -1e30f};
  float lrow[4] = {0.f, 0.f, 0.f, 0.f};  // per-lane partial; reduced at end

  const int nt = 2 * qb + 2;
  uint4 kr0, vr0;
  {
    const u16* kp = kbase + (size_t)(ks_r)*3072 + ks_c;
    kr0 = *(const uint4*)kp;
    const u16* vp = vbase + (size_t)(vs_s)*3072 + vs_d;
    vr0 = *(const uint4*)vp;
  }
  for (int t = 0; t < nt; ++t) {
    const int pb = t & 1;
    // write tile t's prefetched regs into buf[pb]; last reads of buf[pb]
    // (compute t-2) are fenced by the barrier inside iteration t-1.
    *(uint4*)(&sK[pb][ks_r][ks_c]) = kr0;
    {
      union { uint4 q4; u16 e[8]; } va;
      va.q4 = vr0;
#pragma unroll
      for (int j = 0; j < 8; ++j) sVt[pb][vs_d + j][vs_s] = va.e[j];
    }
    if (t + 1 < nt) {  // T14: issue next tile's global loads
      const u16* kp = kbase + (size_t)((t + 1) * 64 + ks_r) * 3072 + ks_c;
      kr0 = *(const uint4*)kp;
      const u16* vp = vbase + (size_t)((t + 1) * 64 + vs_s) * 3072 + vs_d;
      vr0 = *(const uint4*)vp;
    }
    __syncthreads();  // buf[pb] visible to all; ONLY barrier this tile

    f32x4 st[4];
#pragma unroll
    for (int n = 0; n < 4; ++n) {
      s16x8 k0 = *(const s16x8*)(&sK[pb][n * 16 + l15][g * 8]);
      s16x8 k1 = *(const s16x8*)(&sK[pb][n * 16 + l15][32 + g * 8]);
      f32x4 a = {};
      a = __builtin_amdgcn_mfma_f32_16x16x32_bf16(qf0, k0, a, 0, 0, 0);
      a = __builtin_amdgcn_mfma_f32_16x16x32_bf16(qf1, k1, a, 0, 0, 0);
      st[n] = a;
    }
    if (t >= 2 * qb) {  // diagonal spans the last two tiles (absolute idx)
#pragma unroll
      for (int n = 0; n < 4; ++n)
#pragma unroll
        for (int i = 0; i < 4; ++i) {
          const int s_abs = t * 64 + n * 16 + l15;
          const int q_abs = qw + 4 * g + i;
          if (s_abs > q_abs) st[n][i] = -1e30f;
        }
    }
    float pm[4];
#pragma unroll
    for (int i = 0; i < 4; ++i)
      pm[i] = fmaxf(fmaxf(st[0][i], st[1][i]), fmaxf(st[2][i], st[3][i]));
#pragma unroll
    for (int msk = 1; msk < 16; msk <<= 1)
#pragma unroll
      for (int i = 0; i < 4; ++i) pm[i] = fmaxf(pm[i], __shfl_xor(pm[i], msk));
    bool need = false;  // T13 defer-max
#pragma unroll
    for (int i = 0; i < 4; ++i) need = need || (pm[i] > mrow[i] + 12.f);
    if (__any(need)) {
#pragma unroll
      for (int i = 0; i < 4; ++i) {
        const float mnew = fmaxf(mrow[i], pm[i]);
        const float corr = exp2f((mrow[i] - mnew) * c);
        mrow[i] = mnew;
        lrow[i] *= corr;
#pragma unroll
        for (int dt = 0; dt < 4; ++dt) oacc[dt][i] *= corr;
      }
    }
    float p[4][4];
#pragma unroll
    for (int n = 0; n < 4; ++n)
#pragma unroll
      for (int i = 0; i < 4; ++i) p[n][i] = exp2f((st[n][i] - mrow[i]) * c);
#pragma unroll
    for (int i = 0; i < 4; ++i)
      lrow[i] += (p[0][i] + p[1][i]) + (p[2][i] + p[3][i]);
#pragma unroll
    for (int n = 0; n < 4; ++n)
#pragma unroll
      for (int i = 0; i < 4; ++i)
        sP[w][4 * g + i][n * 16 + l15] = f2bf(p[n][i]);
    s16x8 pf0 = *(const s16x8*)(&sP[w][l15][g * 8]);
    s16x8 pf1 = *(const s16x8*)(&sP[w][l15][32 + g * 8]);
#pragma unroll
    for (int dt = 0; dt < 4; ++dt) {
      s16x8 vf0 = ld_s16x8_a8(&sVt[pb][dt * 16 + l15][g * 8]);
      s16x8 vf1 = ld_s16x8_a8(&sVt[pb][dt * 16 + l15][32 + g * 8]);
      oacc[dt] = __builtin_amdgcn_mfma_f32_16x16x32_bf16(pf0, vf0, oacc[dt], 0, 0, 0);
      oacc[dt] = __builtin_amdgcn_mfma_f32_16x16x32_bf16(pf1, vf1, oacc[dt], 0, 0, 0);
    }
  }

#pragma unroll
  for (int msk = 1; msk < 16; msk <<= 1)
#pragma unroll
    for (int i = 0; i < 4; ++i) lrow[i] += __shfl_xor(lrow[i], msk);
  float inv[4];
#pragma unroll
  for (int i = 0; i < 4; ++i) inv[i] = 1.f / lrow[i];
#pragma unroll
  for (int dt = 0; dt < 4; ++dt)
#pragma unroll
    for (int i = 0; i < 4; ++i) {
      const size_t row = (size_t)(b * 2048 + qw + 4 * g + i);
      o[row * 1024 + h * 64 + dt * 16 + l15] = f2bf(oacc[dt][i] * inv[i]);
    }
}

// ---------------------------------------------------------------------------
extern "C" void kernel_launch(void* const* d_in, const int* in_sizes, int n_in,
                              void* d_out, int out_size, void* d_ws, size_t ws_size,
                              hipStream_t stream) {
  const float* x     = (const float*)d_in[0];
  const float* Wq    = (const float*)d_in[1];
  const float* Wk    = (const float*)d_in[2];
  const float* Wv    = (const float*)d_in[3];
  const float* Wproj = (const float*)d_in[4];
  const float* bproj = (const float*)d_in[5];
  const float* W1    = (const float*)d_in[6];
  const float* b1    = (const float*)d_in[7];
  const float* W2    = (const float*)d_in[8];
  const float* b2    = (const float*)d_in[9];
  const float* g1    = (const float*)d_in[10];
  const float* be1   = (const float*)d_in[11];
  const float* g2    = (const float*)d_in[12];
  const float* be2   = (const float*)d_in[13];
  float* out = (float*)d_out;

  u16* WqkvT  = (u16*)d_ws;                    // [3072][1024] bf16
  u16* WprojT = WqkvT + (size_t)3072 * 1024;   // [1024][1024]
  u16* W1T    = WprojT + (size_t)1024 * 1024;  // [4096][1024]
  u16* W2T    = W1T + (size_t)4096 * 1024;     // [1024][4096]
  u16* hbuf   = W2T + (size_t)1024 * 4096;     // [4096][1024]
  u16* qkv    = hbuf + (size_t)4096 * 1024;    // [4096][3072]
  u16* obuf   = qkv + (size_t)4096 * 3072;     // [4096][1024]
  float* x2   = (float*)(obuf + (size_t)4096 * 1024);  // [4096][1024] fp32
  u16* a1     = (u16*)(x2 + (size_t)4096 * 1024);      // [4096][4096]
  float* Pk   = (float*)hbuf;  // FF2 split-K partials (32 MB over hbuf+qkv)

  transpose_all_kernel<<<3072, 256, 0, stream>>>(Wq, Wk, Wv, Wproj, W1, W2,
                                                 WqkvT, WprojT, W1T, W2T);
  ln_kernel<<<4096, 256, 0, stream>>>(x, g1, be1, hbuf);
  gemm256_kernel<0><<<dim3(12, 16), 512, 0, stream>>>(hbuf, WqkvT, nullptr, nullptr, qkv, 4096, 3072, 1024);
  attn_mfma_kernel<<<512, 512, 0, stream>>>(qkv, obuf);
  gemm128d_kernel<2><<<dim3(8, 32), 256, 0, stream>>>(obuf, WprojT, bproj, x, x2, 4096, 1024, 1024, 1024);
  ln_kernel<<<4096, 256, 0, stream>>>(x2, g2, be2, hbuf);
  gemm256_kernel<1><<<dim3(16, 16), 512, 0, stream>>>(hbuf, W1T, b1, nullptr, a1, 4096, 4096, 1024);
  gemm128d_kernel<3><<<dim3(8, 32, 2), 256, 0, stream>>>(a1, W2T, nullptr, nullptr, Pk, 4096, 1024, 2048, 4096);
  combine_kernel<<<4096, 256, 0, stream>>>(Pk, x2, b2, out);
}